// Round 4
// baseline (2238.107 us; speedup 1.0000x reference)
//
#include <hip/hip_runtime.h>
#include <math.h>

#define NTRAJ 32
#define TLEN  64
#define BATCH (NTRAJ*TLEN)   // 2048

__device__ __forceinline__ float eluf(float x){ return x > 0.f ? x : expm1f(x); }
__device__ __forceinline__ float sigmf(float x){ return 1.f/(1.f+expf(-x)); }

// ---------------- conv1: NHWC (C=4) input -> NHWC [2048][42][42][32] ----------
__global__ __launch_bounds__(256) void conv1_kernel(
    const float* __restrict__ in,   // [2048][84][84][4]
    const float* __restrict__ w,    // [3][3][4][32] HWIO
    const float* __restrict__ b,    // [32]
    float* __restrict__ out)        // [2048][42][42][32]
{
    int bid = blockIdx.x;
    bid = (bid & 7)*1764 + (bid >> 3);           // XCD chunk swizzle (14112%8==0)
    int pos = bid*256 + threadIdx.x;             // 3,612,672 exactly
    int n   = pos / (42*42);
    int rem = pos % (42*42);
    int oy  = rem / 42, ox = rem % 42;
    float acc[32];
    #pragma unroll
    for(int o=0;o<32;o++) acc[o] = b[o];
    for(int ky=0; ky<3; ky++){
        int iy = 2*oy + ky;                      // pad_before = 0 (84->42 SAME)
        if(iy >= 84) continue;
        for(int kx=0; kx<3; kx++){
            int ix = 2*ox + kx;
            if(ix >= 84) continue;
            float4 v = *(const float4*)(in + (((n*84 + iy)*84) + ix)*4);
            const float* wq = w + (ky*3 + kx)*128;   // [ci][32]
            #pragma unroll
            for(int o=0;o<32;o++) acc[o] += v.x*wq[o];
            #pragma unroll
            for(int o=0;o<32;o++) acc[o] += v.y*wq[32+o];
            #pragma unroll
            for(int o=0;o<32;o++) acc[o] += v.z*wq[64+o];
            #pragma unroll
            for(int o=0;o<32;o++) acc[o] += v.w*wq[96+o];
        }
    }
    float4* op = (float4*)(out + (size_t)pos*32);
    #pragma unroll
    for(int q=0;q<8;q++)
        op[q] = make_float4(eluf(acc[4*q]), eluf(acc[4*q+1]),
                            eluf(acc[4*q+2]), eluf(acc[4*q+3]));
}

// ---------------- conv2/3/4: NHWC 32ch -> NHWC 32ch ---------------------------
template<int IH, int IW, int OH, int OW, int PB>
__global__ __launch_bounds__(256) void convN_kernel(
    const float* __restrict__ in,   // [BATCH][IH][IW][32]
    const float* __restrict__ w,    // [3][3][32][32] HWIO
    const float* __restrict__ b,    // [32]
    float* __restrict__ out)        // [BATCH][OH][OW][32]
{
    int bid = blockIdx.x;
    const int cpx = gridDim.x >> 3;              // all conv grids %8 == 0
    bid = (bid & 7)*cpx + (bid >> 3);            // XCD chunk swizzle
    int pos = bid*256 + threadIdx.x;
    if(pos >= BATCH*OH*OW) return;
    int n   = pos / (OH*OW);
    int rem = pos % (OH*OW);
    int oy  = rem / OW, ox = rem % OW;
    float acc[32];
    #pragma unroll
    for(int o=0;o<32;o++) acc[o] = b[o];
    for(int ky=0; ky<3; ky++){
        int iy = 2*oy + ky - PB;
        if(iy < 0 || iy >= IH) continue;
        for(int kx=0; kx<3; kx++){
            int ix = 2*ox + kx - PB;
            if(ix < 0 || ix >= IW) continue;
            const float4* ip = (const float4*)(in + ((size_t)(n*IH + iy)*IW + ix)*32);
            const float* wp = w + (ky*3 + kx)*1024;  // [ci][32]
            #pragma unroll
            for(int c4=0;c4<8;c4++){
                float4 x = ip[c4];
                const float* wq = wp + c4*128;       // uniform -> s_load
                #pragma unroll
                for(int o=0;o<32;o++) acc[o] += x.x*wq[o];
                #pragma unroll
                for(int o=0;o<32;o++) acc[o] += x.y*wq[32+o];
                #pragma unroll
                for(int o=0;o<32;o++) acc[o] += x.z*wq[64+o];
                #pragma unroll
                for(int o=0;o<32;o++) acc[o] += x.w*wq[96+o];
            }
        }
    }
    float4* op = (float4*)(out + (size_t)pos*32);
    #pragma unroll
    for(int q=0;q<8;q++)
        op[q] = make_float4(eluf(acc[4*q]), eluf(acc[4*q+1]),
                            eluf(acc[4*q+2]), eluf(acc[4*q+3]));
}

// ---------------- conv4 NHWC ([nt][feat]) -> A_T[feat=1152][row=2048] ---------
// Also zeroes the tagged h-exchange buffer every launch (poison/rep safe).
__global__ __launch_bounds__(256) void relayout_kernel(
    const float* __restrict__ p4,   // [2048(nt)][1152(f)]
    float* __restrict__ at,         // [1152][2048], row r = t*32+n
    unsigned long long* __restrict__ hbuf)  // [64][32][256] tagged
{
    int i = blockIdx.x*256 + threadIdx.x;   // 2,359,296 exactly
    if(i < 64*8192) hbuf[i] = 0ull;         // clear tags (kernel-end WB orders)
    int f = i >> 11, r = i & 2047;          // write coalesced over r
    int tt = r >> 5, n = r & 31;            // r = t*32 + n
    int nt = n*64 + tt;
    at[i] = p4[nt*1152 + f];
}

// ---------------- gate pre-projection: gx[r][1024] = A_T^T @ Wx + b ----------
__global__ __launch_bounds__(256) void gx_gemm_kernel(
    const float* __restrict__ at,   // [1152][2048]
    const float* __restrict__ lw,   // [1408][1024] (rows 0..1151 = Wx)
    const float* __restrict__ lb,   // [1024]
    float* __restrict__ gx)         // [2048][1024], row r = t*32+n
{
    int lane = threadIdx.x & 63;
    int wv   = threadIdx.x >> 6;
    int r0   = blockIdx.x * 16;                    // grid.x = 128
    int oc   = blockIdx.y*256 + wv*64 + lane;      // grid.y = 4
    float acc[16];
    float bias = lb[oc];
    #pragma unroll
    for(int i=0;i<16;i++) acc[i] = bias;
    #pragma unroll 4
    for(int k=0;k<1152;k++){
        float wval = lw[k*1024 + oc];              // coalesced v-load
        const float* ap = at + k*2048 + r0;        // uniform -> s_load_dwordx16
        #pragma unroll
        for(int i=0;i<16;i++) acc[i] += ap[i] * wval;
    }
    #pragma unroll
    for(int i=0;i<16;i++) gx[(r0+i)*1024 + oc] = acc[i];  // coalesced
}

// ---------------- cooperative weight-stationary LSTM, 32 WGs ------------------
// WG g owns units [8g,8g+8) = 32 gate cols. Thread = 2 trajs x 2 cols (2x2
// blocking: 4 b128 per 16 FMA). Cross-WG h exchange is fence-free dataflow:
// each h element is a self-tagged u64 (hi=step+1, lo=float bits) written as a
// relaxed agent-scope atomic (write-through; no wbl2/inv). Readers poll tags;
// single-word atomicity makes tag-valid => data-valid. Depth-64 buffer kills
// all WAR hazards; fast WGs simply run ahead (no barrier skew).
__global__ __launch_bounds__(256) void lstm_coop_kernel(
    const float* __restrict__ gx,   // [2048][1024], row = st*32+n (bias folded)
    const float* __restrict__ lw,   // [1408][1024]; rows 1152.. = Wh
    const float* __restrict__ c0,   // [32][256]
    const float* __restrict__ h0,   // [32][256]
    float* __restrict__ feats,      // [2048][256], row = n*64+st
    unsigned long long* __restrict__ hbuf)  // [64][32][256] tagged, pre-zeroed
{
    __shared__ float hs[32*260];    // h(st-1), row stride 260 (bank-spread)
    __shared__ float wp[16*516];    // Wh pairs: [cp][k2] f4 {w[2k2][c0],w[2k2][c1],
                                    //  w[2k2+1][c0],w[2k2+1][c1]}, stride 129 f4
    __shared__ float gl[32*33];     // gate buffer

    const int wg = blockIdx.x;      // 0..31
    const int t  = threadIdx.x;
    const float* wh = lw + 1152*1024;

    // ---- one-time: Wh slice (256 k x 32 cols) -> paired LDS layout
    for(int i=0;i<32;i++){
        int e = t + 256*i;                  // 8192 elements
        int k = e >> 5, c = e & 31;
        int gc = (c>>3)*256 + wg*8 + (c&7);
        wp[(c>>1)*516 + (k>>1)*4 + (k&1)*2 + (c&1)] = wh[k*1024 + gc];
    }
    // ---- persistent cell state: thread t owns (un = t>>3, uu = t&7)
    const int un = t >> 3, uu = t & 7;
    float cst = c0[un*256 + wg*8 + uu];

    // ---- matvec tile: 2 trajs x 2 cols per thread
    const int np = t >> 4, cp = t & 15;
    const int n0 = 2*np, n1 = 2*np + 1;
    const int c0l = 2*cp, c1l = 2*cp + 1;
    const int g0 = (c0l>>3)*256 + wg*8 + (c0l&7);
    const int g1 = (c1l>>3)*256 + wg*8 + (c1l&7);

    const float4* hs4 = (const float4*)hs;
    const float4* wp4 = (const float4*)wp;
    __syncthreads();                        // wp ready

    for(int st=0; st<64; ++st){
        // gx loads issued early (plain cached loads; used after matvec)
        const float* gr0 = gx + (size_t)(st*32 + n0)*1024;
        const float* gr1 = gx + (size_t)(st*32 + n1)*1024;
        float gx00 = gr0[g0], gx01 = gr0[g1];
        float gx10 = gr1[g0], gx11 = gr1[g1];

        // ---- stage h(st-1) into LDS
        if(st == 0){
            const float4* hp4 = (const float4*)h0;
            #pragma unroll
            for(int i=0;i<8;i++){
                int q = t + 256*i;          // 2048 f4
                int row = q >> 6, col4 = q & 63;
                ((float4*)hs)[row*65 + col4] = hp4[q];
            }
        } else {
            const unsigned long long* src = hbuf + (size_t)(st-1)*8192;
            const unsigned tag = (unsigned)st;
            #pragma unroll
            for(int i=0;i<32;i++){
                int q = i*256 + t;          // row i, col t (coalesced)
                unsigned long long v = __hip_atomic_load(&src[q],
                    __ATOMIC_RELAXED, __HIP_MEMORY_SCOPE_AGENT);
                unsigned spins = 0;
                while((unsigned)(v >> 32) != tag){
                    __builtin_amdgcn_s_sleep(1);
                    v = __hip_atomic_load(&src[q],
                        __ATOMIC_RELAXED, __HIP_MEMORY_SCOPE_AGENT);
                    if(++spins > (1u<<23)) break;   // failsafe: no hard hang
                }
                hs[i*260 + t] = __uint_as_float((unsigned)v);
            }
        }
        __syncthreads();                    // hs complete

        // ---- matvec: 4 b128 -> 16 FMA; h rows conflict-free, w pairs 2-way
        float a00=0.f, a01=0.f, a10=0.f, a11=0.f;
        const float4* h0r = hs4 + n0*65;
        const float4* h1r = hs4 + n1*65;
        const float4* wr  = wp4 + cp*129;
        #pragma unroll 8
        for(int k4=0;k4<64;k4++){
            float4 A = wr[2*k4], B = wr[2*k4+1];
            float4 x = h0r[k4], y = h1r[k4];
            a00 += x.x*A.x + x.y*A.z + x.z*B.x + x.w*B.z;
            a01 += x.x*A.y + x.y*A.w + x.z*B.y + x.w*B.w;
            a10 += y.x*A.x + y.y*A.z + y.z*B.x + y.w*B.z;
            a11 += y.x*A.y + y.y*A.w + y.z*B.y + y.w*B.w;
        }
        gl[n0*33 + c0l] = a00 + gx00;
        gl[n0*33 + c1l] = a01 + gx01;
        gl[n1*33 + c0l] = a10 + gx10;
        gl[n1*33 + c1l] = a11 + gx11;
        __syncthreads();                    // gates complete

        // ---- update: thread owns (un, uu)
        {
            float i_ = gl[un*33 +      uu];
            float j_ = gl[un*33 +  8 + uu];
            float f_ = gl[un*33 + 16 + uu];
            float o_ = gl[un*33 + 24 + uu];
            cst = cst*sigmf(f_ + 1.f) + sigmf(i_)*tanhf(j_);
            float h = tanhf(cst)*sigmf(o_);
            int col = wg*8 + uu;
            feats[(un*64 + st)*256 + col] = h;     // plain (read post-kernel)
            unsigned long long pv =
                ((unsigned long long)(unsigned)(st+1) << 32) |
                (unsigned long long)__float_as_uint(h);
            __hip_atomic_store(&hbuf[(size_t)st*8192 + un*256 + col], pv,
                               __ATOMIC_RELAXED, __HIP_MEMORY_SCOPE_AGENT);
        }
        __syncthreads();                    // protect hs/gl from next-step writes
    }
}

// ---------------- final FC: logits[p][18] = feats[p] @ fc_w + fc_b ----------
__global__ __launch_bounds__(64) void fc_kernel(
    const float* __restrict__ feats, const float* __restrict__ fw,
    const float* __restrict__ fb,    float* __restrict__ out)
{
    __shared__ float h[256];
    int p = blockIdx.x, t = threadIdx.x;
    *(float4*)&h[t*4] = *(const float4*)(feats + p*256 + t*4);
    __syncthreads();
    if(t < 18){
        float acc = fb[t];
        for(int k=0;k<256;k++) acc += h[k]*fw[k*18 + t];
        out[p*18 + t] = acc;
    }
}

extern "C" void kernel_launch(void* const* d_in, const int* in_sizes, int n_in,
                              void* d_out, int out_size, void* d_ws, size_t ws_size,
                              hipStream_t stream) {
    const float* inp = (const float*)d_in[0];
    const float* w1  = (const float*)d_in[1];  const float* b1 = (const float*)d_in[2];
    const float* w2  = (const float*)d_in[3];  const float* b2 = (const float*)d_in[4];
    const float* w3  = (const float*)d_in[5];  const float* b3 = (const float*)d_in[6];
    const float* w4  = (const float*)d_in[7];  const float* b4 = (const float*)d_in[8];
    const float* lw  = (const float*)d_in[9];  const float* lb = (const float*)d_in[10];
    const float* fw  = (const float*)d_in[11]; const float* fb = (const float*)d_in[12];
    const float* c0  = (const float*)d_in[13]; const float* h0 = (const float*)d_in[14];
    float* out = (float*)d_out;
    float* ws  = (float*)d_ws;

    const size_t n1 = (size_t)32*3612672;   // conv1 out (NHWC, same float count)
    const size_t n3 = (size_t)32*247808;    // conv3 out
    const size_t n4 = (size_t)32*73728;     // conv4 out

    float* p1 = ws;
    float* p2 = p1 + n1;                    // conv2 out (28.9M floats)
    float* p3 = ws;                         // reuse p1 region (conv3 reads only p2)
    float* p4 = p3 + n3;
    float* at = p4 + n4;                    // [1152][2048]
    float* gxb   = at  + (size_t)1152*2048; // [2048][1024]
    float* feats = gxb + (size_t)2048*1024; // [2048][256]
    unsigned long long* hbuf =
        (unsigned long long*)(feats + (size_t)2048*256);  // [64][32][256] u64

    conv1_kernel<<<14112,256,0,stream>>>(inp, w1, b1, p1);
    convN_kernel<42,42,21,21,0><<<3528,256,0,stream>>>(p1, w2, b2, p2);
    convN_kernel<21,21,11,11,1><<<968,256,0,stream>>>(p2, w3, b3, p3);
    convN_kernel<11,11, 6, 6,1><<<288,256,0,stream>>>(p3, w4, b4, p4);
    relayout_kernel<<<9216,256,0,stream>>>(p4, at, hbuf);
    gx_gemm_kernel<<<dim3(128,4),256,0,stream>>>(at, lw, lb, gxb);
    lstm_coop_kernel<<<32,256,0,stream>>>(gxb, lw, c0, h0, feats, hbuf);
    fc_kernel<<<2048,64,0,stream>>>(feats, fw, fb, out);
}

// Round 5
// 1783.610 us; speedup vs baseline: 1.2548x; 1.2548x over previous
//
#include <hip/hip_runtime.h>
#include <math.h>

#define NTRAJ 32
#define TLEN  64
#define BATCH (NTRAJ*TLEN)   // 2048

__device__ __forceinline__ float eluf(float x){ return x > 0.f ? x : expm1f(x); }
__device__ __forceinline__ float sigmf(float x){ return 1.f/(1.f+expf(-x)); }

// ---------------- conv1: NHWC (C=4) input -> NHWC [2048][42][42][32] ----------
__global__ __launch_bounds__(256) void conv1_kernel(
    const float* __restrict__ in,   // [2048][84][84][4]
    const float* __restrict__ w,    // [3][3][4][32] HWIO
    const float* __restrict__ b,    // [32]
    float* __restrict__ out)        // [2048][42][42][32]
{
    int bid = blockIdx.x;
    bid = (bid & 7)*1764 + (bid >> 3);           // XCD chunk swizzle (14112%8==0)
    int pos = bid*256 + threadIdx.x;             // 3,612,672 exactly
    int n   = pos / (42*42);
    int rem = pos % (42*42);
    int oy  = rem / 42, ox = rem % 42;
    float acc[32];
    #pragma unroll
    for(int o=0;o<32;o++) acc[o] = b[o];
    for(int ky=0; ky<3; ky++){
        int iy = 2*oy + ky;                      // pad_before = 0 (84->42 SAME)
        if(iy >= 84) continue;
        for(int kx=0; kx<3; kx++){
            int ix = 2*ox + kx;
            if(ix >= 84) continue;
            float4 v = *(const float4*)(in + (((n*84 + iy)*84) + ix)*4);
            const float* wq = w + (ky*3 + kx)*128;   // [ci][32]
            #pragma unroll
            for(int o=0;o<32;o++) acc[o] += v.x*wq[o];
            #pragma unroll
            for(int o=0;o<32;o++) acc[o] += v.y*wq[32+o];
            #pragma unroll
            for(int o=0;o<32;o++) acc[o] += v.z*wq[64+o];
            #pragma unroll
            for(int o=0;o<32;o++) acc[o] += v.w*wq[96+o];
        }
    }
    float4* op = (float4*)(out + (size_t)pos*32);
    #pragma unroll
    for(int q=0;q<8;q++)
        op[q] = make_float4(eluf(acc[4*q]), eluf(acc[4*q+1]),
                            eluf(acc[4*q+2]), eluf(acc[4*q+3]));
}

// ---------------- conv2/3/4: NHWC 32ch -> NHWC 32ch ---------------------------
template<int IH, int IW, int OH, int OW, int PB>
__global__ __launch_bounds__(256) void convN_kernel(
    const float* __restrict__ in,   // [BATCH][IH][IW][32]
    const float* __restrict__ w,    // [3][3][32][32] HWIO
    const float* __restrict__ b,    // [32]
    float* __restrict__ out)        // [BATCH][OH][OW][32]
{
    int bid = blockIdx.x;
    const int cpx = gridDim.x >> 3;              // all conv grids %8 == 0
    bid = (bid & 7)*cpx + (bid >> 3);            // XCD chunk swizzle
    int pos = bid*256 + threadIdx.x;
    if(pos >= BATCH*OH*OW) return;
    int n   = pos / (OH*OW);
    int rem = pos % (OH*OW);
    int oy  = rem / OW, ox = rem % OW;
    float acc[32];
    #pragma unroll
    for(int o=0;o<32;o++) acc[o] = b[o];
    for(int ky=0; ky<3; ky++){
        int iy = 2*oy + ky - PB;
        if(iy < 0 || iy >= IH) continue;
        for(int kx=0; kx<3; kx++){
            int ix = 2*ox + kx - PB;
            if(ix < 0 || ix >= IW) continue;
            const float4* ip = (const float4*)(in + ((size_t)(n*IH + iy)*IW + ix)*32);
            const float* wp = w + (ky*3 + kx)*1024;  // [ci][32]
            #pragma unroll
            for(int c4=0;c4<8;c4++){
                float4 x = ip[c4];
                const float* wq = wp + c4*128;       // uniform -> s_load
                #pragma unroll
                for(int o=0;o<32;o++) acc[o] += x.x*wq[o];
                #pragma unroll
                for(int o=0;o<32;o++) acc[o] += x.y*wq[32+o];
                #pragma unroll
                for(int o=0;o<32;o++) acc[o] += x.z*wq[64+o];
                #pragma unroll
                for(int o=0;o<32;o++) acc[o] += x.w*wq[96+o];
            }
        }
    }
    float4* op = (float4*)(out + (size_t)pos*32);
    #pragma unroll
    for(int q=0;q<8;q++)
        op[q] = make_float4(eluf(acc[4*q]), eluf(acc[4*q+1]),
                            eluf(acc[4*q+2]), eluf(acc[4*q+3]));
}

// ---------------- conv4 NHWC ([nt][feat]) -> A_T[feat=1152][row=2048] ---------
// Also zeroes the tagged h-exchange buffer every launch (poison/rep safe;
// end-of-kernel release writes the zeros back before lstm's L3 atomic reads).
__global__ __launch_bounds__(256) void relayout_kernel(
    const float* __restrict__ p4,   // [2048(nt)][1152(f)]
    float* __restrict__ at,         // [1152][2048], row r = t*32+n
    unsigned long long* __restrict__ hbuf)  // [64][32][256] tagged
{
    int i = blockIdx.x*256 + threadIdx.x;   // 2,359,296 exactly
    if(i < 64*8192) hbuf[i] = 0ull;         // clear tags
    int f = i >> 11, r = i & 2047;          // write coalesced over r
    int tt = r >> 5, n = r & 31;            // r = t*32 + n
    int nt = n*64 + tt;
    at[i] = p4[nt*1152 + f];
}

// ---------------- gate pre-projection: gx[r][1024] = A_T^T @ Wx + b ----------
__global__ __launch_bounds__(256) void gx_gemm_kernel(
    const float* __restrict__ at,   // [1152][2048]
    const float* __restrict__ lw,   // [1408][1024] (rows 0..1151 = Wx)
    const float* __restrict__ lb,   // [1024]
    float* __restrict__ gx)         // [2048][1024], row r = t*32+n
{
    int lane = threadIdx.x & 63;
    int wv   = threadIdx.x >> 6;
    int r0   = blockIdx.x * 16;                    // grid.x = 128
    int oc   = blockIdx.y*256 + wv*64 + lane;      // grid.y = 4
    float acc[16];
    float bias = lb[oc];
    #pragma unroll
    for(int i=0;i<16;i++) acc[i] = bias;
    #pragma unroll 4
    for(int k=0;k<1152;k++){
        float wval = lw[k*1024 + oc];              // coalesced v-load
        const float* ap = at + k*2048 + r0;        // uniform -> s_load_dwordx16
        #pragma unroll
        for(int i=0;i<16;i++) acc[i] += ap[i] * wval;
    }
    #pragma unroll
    for(int i=0;i<16;i++) gx[(r0+i)*1024 + oc] = acc[i];  // coalesced
}

// ---------------- cooperative weight-stationary LSTM, 32 WGs ------------------
// WG g owns units [8g,8g+8) = 32 gate cols. Thread = 2 trajs x 2 cols (2x2
// blocking: 4 b128 per 16 FMA). Cross-WG h exchange is fence-free dataflow:
// each h element is a self-tagged u64 (hi=step+1, lo=float bits), relaxed
// agent-scope atomics (no wbl2/inv ever). KEY FIX vs r4: the 32 staged loads
// are issued as ONE pipelined batch (independent loads, single vmcnt drain),
// with a rare retry pass for stale tags -- not 32 serialized spin loops.
__global__ __launch_bounds__(256) void lstm_coop_kernel(
    const float* __restrict__ gx,   // [2048][1024], row = st*32+n (bias folded)
    const float* __restrict__ lw,   // [1408][1024]; rows 1152.. = Wh
    const float* __restrict__ c0,   // [32][256]
    const float* __restrict__ h0,   // [32][256]
    float* __restrict__ feats,      // [2048][256], row = n*64+st
    unsigned long long* __restrict__ hbuf)  // [64][32][256] tagged, pre-zeroed
{
    __shared__ float hs[32*260];    // h(st-1), row stride 260 (bank-spread)
    __shared__ float wp[16*516];    // Wh pairs: [cp][k2] f4 {w[2k2][c0],w[2k2][c1],
                                    //  w[2k2+1][c0],w[2k2+1][c1]}, stride 129 f4
    __shared__ float gl[32*33];     // gate buffer

    const int wg = blockIdx.x;      // 0..31
    const int t  = threadIdx.x;
    const float* wh = lw + 1152*1024;

    // ---- one-time: Wh slice (256 k x 32 cols) -> paired LDS layout
    for(int i=0;i<32;i++){
        int e = t + 256*i;                  // 8192 elements
        int k = e >> 5, c = e & 31;
        int gc = (c>>3)*256 + wg*8 + (c&7);
        wp[(c>>1)*516 + (k>>1)*4 + (k&1)*2 + (c&1)] = wh[k*1024 + gc];
    }
    // ---- persistent cell state: thread t owns (un = t>>3, uu = t&7)
    const int un = t >> 3, uu = t & 7;
    float cst = c0[un*256 + wg*8 + uu];

    // ---- matvec tile: 2 trajs x 2 cols per thread
    const int np = t >> 4, cp = t & 15;
    const int n0 = 2*np, n1 = 2*np + 1;
    const int c0l = 2*cp, c1l = 2*cp + 1;
    const int g0 = (c0l>>3)*256 + wg*8 + (c0l&7);
    const int g1 = (c1l>>3)*256 + wg*8 + (c1l&7);

    const float4* hs4 = (const float4*)hs;
    const float4* wp4 = (const float4*)wp;
    __syncthreads();                        // wp ready

    for(int st=0; st<64; ++st){
        // gx loads issued early (plain cached loads; used after matvec)
        const float* gr0 = gx + (size_t)(st*32 + n0)*1024;
        const float* gr1 = gx + (size_t)(st*32 + n1)*1024;
        float gx00 = gr0[g0], gx01 = gr0[g1];
        float gx10 = gr1[g0], gx11 = gr1[g1];

        // ---- stage h(st-1) into LDS
        if(st == 0){
            const float4* hp4 = (const float4*)h0;
            #pragma unroll
            for(int i=0;i<8;i++){
                int q = t + 256*i;          // 2048 f4
                int row = q >> 6, col4 = q & 63;
                ((float4*)hs)[row*65 + col4] = hp4[q];
            }
        } else {
            const unsigned long long* src = hbuf + (size_t)(st-1)*8192;
            const unsigned tag = (unsigned)st;
            unsigned long long v[32];
            // batched issue: 32 independent coalesced loads, one drain
            #pragma unroll
            for(int i=0;i<32;i++)
                v[i] = __hip_atomic_load(&src[i*256 + t],
                    __ATOMIC_RELAXED, __HIP_MEMORY_SCOPE_AGENT);
            // retry pass: only stale entries re-load (rare in steady state)
            unsigned spins = 0;
            for(;;){
                bool ok = true;
                #pragma unroll
                for(int i=0;i<32;i++){
                    if((unsigned)(v[i] >> 32) != tag){
                        v[i] = __hip_atomic_load(&src[i*256 + t],
                            __ATOMIC_RELAXED, __HIP_MEMORY_SCOPE_AGENT);
                        ok = false;
                    }
                }
                if(ok) break;
                __builtin_amdgcn_s_sleep(1);
                if(++spins > (1u<<21)) break;       // failsafe: no hard hang
            }
            #pragma unroll
            for(int i=0;i<32;i++)
                hs[i*260 + t] = __uint_as_float((unsigned)v[i]);
        }
        __syncthreads();                    // hs complete

        // ---- matvec: 4 b128 -> 16 FMA; h rows conflict-free, w pairs 2-way
        float a00=0.f, a01=0.f, a10=0.f, a11=0.f;
        const float4* h0r = hs4 + n0*65;
        const float4* h1r = hs4 + n1*65;
        const float4* wr  = wp4 + cp*129;
        #pragma unroll 8
        for(int k4=0;k4<64;k4++){
            float4 A = wr[2*k4], B = wr[2*k4+1];
            float4 x = h0r[k4], y = h1r[k4];
            a00 += x.x*A.x + x.y*A.z + x.z*B.x + x.w*B.z;
            a01 += x.x*A.y + x.y*A.w + x.z*B.y + x.w*B.w;
            a10 += y.x*A.x + y.y*A.z + y.z*B.x + y.w*B.z;
            a11 += y.x*A.y + y.y*A.w + y.z*B.y + y.w*B.w;
        }
        gl[n0*33 + c0l] = a00 + gx00;
        gl[n0*33 + c1l] = a01 + gx01;
        gl[n1*33 + c0l] = a10 + gx10;
        gl[n1*33 + c1l] = a11 + gx11;
        __syncthreads();                    // gates complete

        // ---- update: thread owns (un, uu)
        {
            float i_ = gl[un*33 +      uu];
            float j_ = gl[un*33 +  8 + uu];
            float f_ = gl[un*33 + 16 + uu];
            float o_ = gl[un*33 + 24 + uu];
            cst = cst*sigmf(f_ + 1.f) + sigmf(i_)*tanhf(j_);
            float h = tanhf(cst)*sigmf(o_);
            int col = wg*8 + uu;
            feats[(un*64 + st)*256 + col] = h;     // plain (read post-kernel)
            unsigned long long pv =
                ((unsigned long long)(unsigned)(st+1) << 32) |
                (unsigned long long)__float_as_uint(h);
            __hip_atomic_store(&hbuf[(size_t)st*8192 + un*256 + col], pv,
                               __ATOMIC_RELAXED, __HIP_MEMORY_SCOPE_AGENT);
        }
        __syncthreads();                    // protect hs/gl from next-step writes
    }
}

// ---------------- final FC: logits[p][18] = feats[p] @ fc_w + fc_b ----------
__global__ __launch_bounds__(64) void fc_kernel(
    const float* __restrict__ feats, const float* __restrict__ fw,
    const float* __restrict__ fb,    float* __restrict__ out)
{
    __shared__ float h[256];
    int p = blockIdx.x, t = threadIdx.x;
    *(float4*)&h[t*4] = *(const float4*)(feats + p*256 + t*4);
    __syncthreads();
    if(t < 18){
        float acc = fb[t];
        for(int k=0;k<256;k++) acc += h[k]*fw[k*18 + t];
        out[p*18 + t] = acc;
    }
}

extern "C" void kernel_launch(void* const* d_in, const int* in_sizes, int n_in,
                              void* d_out, int out_size, void* d_ws, size_t ws_size,
                              hipStream_t stream) {
    const float* inp = (const float*)d_in[0];
    const float* w1  = (const float*)d_in[1];  const float* b1 = (const float*)d_in[2];
    const float* w2  = (const float*)d_in[3];  const float* b2 = (const float*)d_in[4];
    const float* w3  = (const float*)d_in[5];  const float* b3 = (const float*)d_in[6];
    const float* w4  = (const float*)d_in[7];  const float* b4 = (const float*)d_in[8];
    const float* lw  = (const float*)d_in[9];  const float* lb = (const float*)d_in[10];
    const float* fw  = (const float*)d_in[11]; const float* fb = (const float*)d_in[12];
    const float* c0  = (const float*)d_in[13]; const float* h0 = (const float*)d_in[14];
    float* out = (float*)d_out;
    float* ws  = (float*)d_ws;

    const size_t n1 = (size_t)32*3612672;   // conv1 out (NHWC, same float count)
    const size_t n3 = (size_t)32*247808;    // conv3 out
    const size_t n4 = (size_t)32*73728;     // conv4 out

    float* p1 = ws;
    float* p2 = p1 + n1;                    // conv2 out (28.9M floats)
    float* p3 = ws;                         // reuse p1 region (conv3 reads only p2)
    float* p4 = p3 + n3;
    float* at = p4 + n4;                    // [1152][2048]
    float* gxb   = at  + (size_t)1152*2048; // [2048][1024]
    float* feats = gxb + (size_t)2048*1024; // [2048][256]
    unsigned long long* hbuf =
        (unsigned long long*)(feats + (size_t)2048*256);  // [64][32][256] u64

    conv1_kernel<<<14112,256,0,stream>>>(inp, w1, b1, p1);
    convN_kernel<42,42,21,21,0><<<3528,256,0,stream>>>(p1, w2, b2, p2);
    convN_kernel<21,21,11,11,1><<<968,256,0,stream>>>(p2, w3, b3, p3);
    convN_kernel<11,11, 6, 6,1><<<288,256,0,stream>>>(p3, w4, b4, p4);
    relayout_kernel<<<9216,256,0,stream>>>(p4, at, hbuf);
    gx_gemm_kernel<<<dim3(128,4),256,0,stream>>>(at, lw, lb, gxb);
    lstm_coop_kernel<<<32,256,0,stream>>>(gxb, lw, c0, h0, feats, hbuf);
    fc_kernel<<<2048,64,0,stream>>>(feats, fw, fb, out);
}